// Round 10
// baseline (152.296 us; speedup 1.0000x reference)
//
#include <hip/hip_runtime.h>

#define NB     500000            // B: rule neurons
#define NW     8                 // W: weights per rule
#define ND     16                // D: per-neuron dim
#define NTOT   (NB * 4)          // 2,000,000 thread-slots (4 threads/neuron)
#define BLK    256
#define GRID   2048              // 8 blocks/CU, persistent
#define STRIDE (GRID * BLK)      // 524288
#define ITERS  4                 // ceil(NTOT / STRIDE)

typedef float f32x4 __attribute__((ext_vector_type(4)));

// fast tanh: 1 - 2/(exp(2x)+1); exact saturation at +-inf, ~1e-6 abs err
__device__ __forceinline__ float fast_tanh(float x) {
    float e = __expf(2.0f * x);
    return 1.0f - 2.0f * __builtin_amdgcn_rcpf(e + 1.0f);
}

// Persistent kernel: 4 grid-stride iterations, fully unrolled.
// - 4 threads per neuron (thread owns one float4 of the 64B row)
// - next iteration's indices prefetched while current gathers are in flight
// - nontemporal for streamed idx/out so L2 keeps only `values` lines
__global__ __launch_bounds__(BLK) void wrl_kernel(
    const float* __restrict__ values,   // [N_SRC, 16]
    const float* __restrict__ weights,  // [8, 16]
    const int*   __restrict__ indices,  // [8, B]
    float* __restrict__ out)            // [B, 16]
{
    const int tid0 = blockIdx.x * BLK + threadIdx.x;
    const int dq   = tid0 & 3;          // STRIDE % 4 == 0 -> invariant

    // weights in registers (broadcast, L1-resident)
    f32x4 wreg[NW];
#pragma unroll
    for (int w = 0; w < NW; ++w)
        wreg[w] = *reinterpret_cast<const f32x4*>(weights + w * ND + dq * 4);

    // stage 0: indices for first iteration
    int tid = tid0;
    int bC  = (tid < NTOT ? tid : NTOT - 1) >> 2;
    int idxC[NW];
#pragma unroll
    for (int w = 0; w < NW; ++w)
        idxC[w] = __builtin_nontemporal_load(&indices[(size_t)w * NB + bC]);

#pragma unroll
    for (int it = 0; it < ITERS; ++it) {
        const bool act = (tid < NTOT);
        const int  b   = bC;

        // issue current gathers (addresses from idxC captured here)
        f32x4 v[NW];
#pragma unroll
        for (int w = 0; w < NW; ++w)
            v[w] = *reinterpret_cast<const f32x4*>(
                values + (size_t)idxC[w] * ND + dq * 4);

        // prefetch next iteration's indices while gathers are in flight
        const int tidN = tid + STRIDE;
        if (it < ITERS - 1) {
            const int bN = (tidN < NTOT ? tidN : NTOT - 1) >> 2;
#pragma unroll
            for (int w = 0; w < NW; ++w)
                idxC[w] = __builtin_nontemporal_load(&indices[(size_t)w * NB + bN]);
            bC = bN;
        }

        // consume
        f32x4 acc = (f32x4)(0.f);
#pragma unroll
        for (int w = 0; w < NW; ++w) {
            acc.x += v[w].x * wreg[w].x;  acc.y += v[w].y * wreg[w].y;
            acc.z += v[w].z * wreg[w].z;  acc.w += v[w].w * wreg[w].w;
        }

        if (act) {
            f32x4 o;
            o.x = fast_tanh(acc.x); o.y = fast_tanh(acc.y);
            o.z = fast_tanh(acc.z); o.w = fast_tanh(acc.w);
            __builtin_nontemporal_store(
                o, reinterpret_cast<f32x4*>(out + (size_t)b * ND + dq * 4));
        }
        tid = tidN;
    }
}

extern "C" void kernel_launch(void* const* d_in, const int* in_sizes, int n_in,
                              void* d_out, int out_size, void* d_ws, size_t ws_size,
                              hipStream_t stream) {
    const float* values  = (const float*)d_in[0];
    const float* weights = (const float*)d_in[1];
    const int*   indices = (const int*)d_in[2];
    float* out = (float*)d_out;

    wrl_kernel<<<GRID, BLK, 0, stream>>>(values, weights, indices, out);
}

// Round 13
// 150.554 us; speedup vs baseline: 1.0116x; 1.0116x over previous
//
#include <hip/hip_runtime.h>

#define NSRC 500000            // rows in values
#define NB   500000            // B: rule neurons
#define NW   8                 // W: weights per rule
#define ND   16                // D: per-neuron dim

typedef _Float16 f16;
typedef f16   f16x4 __attribute__((ext_vector_type(4)));
typedef float f32x4 __attribute__((ext_vector_type(4)));

// fast tanh: 1 - 2/(exp(2x)+1); exact saturation at +-inf, ~1e-6 abs err
__device__ __forceinline__ float fast_tanh(float x) {
    float e = __expf(2.0f * x);
    return 1.0f - 2.0f * __builtin_amdgcn_rcpf(e + 1.0f);
}

// ---- Phase 1: values fp32 -> fp16 table in d_ws (RTN), 4 elems/thread ----
__global__ __launch_bounds__(256) void cvt_kernel(
    const float* __restrict__ src, f16* __restrict__ dst)
{
    const int t = blockIdx.x * 256 + threadIdx.x;     // 2,000,000 quads
    if (t >= (NSRC * ND) / 4) return;
    const f32x4 v = *reinterpret_cast<const f32x4*>(src + (size_t)t * 4);
    f16x4 h;
    h.x = (f16)v.x; h.y = (f16)v.y; h.z = (f16)v.z; h.w = (f16)v.w;
    *reinterpret_cast<f16x4*>(dst + (size_t)t * 4) = h;
}

// ---- Phase 2: gather from fp16 table. 4 threads/neuron, 8B/lane rows ----
__global__ __launch_bounds__(256) void wrl_f16_kernel(
    const f16*   __restrict__ values_h, // [NSRC, 16] fp16
    const float* __restrict__ weights,  // [8, 16] fp32
    const int*   __restrict__ indices,  // [8, B]
    float* __restrict__ out)            // [B, 16] fp32
{
    const int tid = blockIdx.x * 256 + threadIdx.x;
    if (tid >= NB * 4) return;
    const int b  = tid >> 2;
    const int dq = tid & 3;

    f32x4 wreg[NW];
#pragma unroll
    for (int w = 0; w < NW; ++w)
        wreg[w] = *reinterpret_cast<const f32x4*>(weights + w * ND + dq * 4);

    int idx[NW];
#pragma unroll
    for (int w = 0; w < NW; ++w)
        idx[w] = indices[w * NB + b];

    f16x4 v[NW];
#pragma unroll
    for (int w = 0; w < NW; ++w)
        v[w] = *reinterpret_cast<const f16x4*>(
            values_h + (size_t)idx[w] * ND + dq * 4);

    f32x4 acc = (f32x4)(0.f);
#pragma unroll
    for (int w = 0; w < NW; ++w) {
        acc.x += (float)v[w].x * wreg[w].x;
        acc.y += (float)v[w].y * wreg[w].y;
        acc.z += (float)v[w].z * wreg[w].z;
        acc.w += (float)v[w].w * wreg[w].w;
    }

    f32x4 o;
    o.x = fast_tanh(acc.x); o.y = fast_tanh(acc.y);
    o.z = fast_tanh(acc.z); o.w = fast_tanh(acc.w);
    *reinterpret_cast<f32x4*>(out + (size_t)b * ND + dq * 4) = o;
}

// ---- Fallback: proven R6 fp32 path (if ws too small for the fp16 table) ----
__global__ __launch_bounds__(256) void wrl_f32_kernel(
    const float* __restrict__ values,
    const float* __restrict__ weights,
    const int*   __restrict__ indices,
    float* __restrict__ out)
{
    const int tid = blockIdx.x * 256 + threadIdx.x;
    if (tid >= NB * 4) return;
    const int b  = tid >> 2;
    const int dq = tid & 3;

    f32x4 wreg[NW];
#pragma unroll
    for (int w = 0; w < NW; ++w)
        wreg[w] = *reinterpret_cast<const f32x4*>(weights + w * ND + dq * 4);

    int idx[NW];
#pragma unroll
    for (int w = 0; w < NW; ++w)
        idx[w] = indices[w * NB + b];

    f32x4 acc = (f32x4)(0.f);
#pragma unroll
    for (int w = 0; w < NW; ++w) {
        const f32x4 v = *reinterpret_cast<const f32x4*>(
            values + (size_t)idx[w] * ND + dq * 4);
        acc.x += v.x * wreg[w].x;  acc.y += v.y * wreg[w].y;
        acc.z += v.z * wreg[w].z;  acc.w += v.w * wreg[w].w;
    }

    f32x4 o;
    o.x = fast_tanh(acc.x); o.y = fast_tanh(acc.y);
    o.z = fast_tanh(acc.z); o.w = fast_tanh(acc.w);
    *reinterpret_cast<f32x4*>(out + (size_t)b * ND + dq * 4) = o;
}

extern "C" void kernel_launch(void* const* d_in, const int* in_sizes, int n_in,
                              void* d_out, int out_size, void* d_ws, size_t ws_size,
                              hipStream_t stream) {
    const float* values  = (const float*)d_in[0];
    const float* weights = (const float*)d_in[1];
    const int*   indices = (const int*)d_in[2];
    float* out = (float*)d_out;

    const size_t tbl_bytes = (size_t)NSRC * ND * sizeof(f16);  // 16 MB
    const int blocks_main = (NB * 4 + 255) / 256;              // 7813

    if (ws_size >= tbl_bytes) {
        f16* values_h = (f16*)d_ws;
        const int blocks_cvt = ((NSRC * ND) / 4 + 255) / 256;  // 7813
        cvt_kernel<<<blocks_cvt, 256, 0, stream>>>(values, values_h);
        wrl_f16_kernel<<<blocks_main, 256, 0, stream>>>(values_h, weights, indices, out);
    } else {
        wrl_f32_kernel<<<blocks_main, 256, 0, stream>>>(values, weights, indices, out);
    }
}